// Round 10
// baseline (134.033 us; speedup 1.0000x reference)
//
#include <hip/hip_runtime.h>

#define NV 1084
#define NPART 64   // precompute partials
#define NBATCH 8   // batches per verts block / joints block

// ws layout (floats):
//  [0, B*192)            A_rel [B][16][12]
//  next NPART*1392       Mpart[p]: M[21][16][4] (1344) + jt[48]
//  next 1344             Mfinal [21][16][4]

__device__ inline void rodrigues9(float x, float y, float z, float R[9]) {
    float n2 = x * x + y * y + z * z + 1e-8f;
    float angle = sqrtf(n2);
    float inv = 1.0f / angle;
    float ax = x * inv, ay = y * inv, az = z * inv;
    float c = cosf(angle), s = sinf(angle);
    float C = 1.0f - c;
    R[0] = 1.0f - C * (ay * ay + az * az);
    R[1] = -s * az + C * ax * ay;
    R[2] = s * ay + C * ax * az;
    R[3] = s * az + C * ax * ay;
    R[4] = 1.0f - C * (ax * ax + az * az);
    R[5] = -s * ax + C * ay * az;
    R[6] = -s * ay + C * ax * az;
    R[7] = s * ax + C * ay * az;
    R[8] = 1.0f - C * (ax * ax + ay * ay);
}

// K1: NPART blocks, partial M/jt over 17 vertices each. No atomics, no memset.
__global__ __launch_bounds__(384) void prep_kernel(
    const float* __restrict__ vt, const float* __restrict__ jreg,
    const float* __restrict__ wts, float* __restrict__ Mpart) {
    int p = blockIdx.x;             // 0..NPART-1
    int t = threadIdx.x;
    int v0 = p * 17, v1 = min(v0 + 17, NV);
    float* mp = Mpart + (size_t)p * 1392;
    if (t < 336) {
        int j = t >> 4, k = t & 15;
        float m0 = 0.f, m1 = 0.f, m2 = 0.f, s = 0.f;
        for (int v = v0; v < v1; ++v) {
            float jw = jreg[v * 21 + j] * wts[v * 16 + k];
            m0 += jw * vt[v * 3 + 0];
            m1 += jw * vt[v * 3 + 1];
            m2 += jw * vt[v * 3 + 2];
            s += jw;
        }
        mp[t * 4 + 0] = m0;
        mp[t * 4 + 1] = m1;
        mp[t * 4 + 2] = m2;
        mp[t * 4 + 3] = s;
    } else if (t < 384) {           // 48 jt entries
        int o = t - 336;
        int j = o / 3, c = o - j * 3;   // j < 16
        float acc = 0.f;
        for (int v = v0; v < v1; ++v) acc += vt[v * 3 + c] * jreg[v * 21 + j];
        mp[1344 + o] = acc;
    }
}

// K2: blocks [0, nFK): FK per (batch, chain-role), euler computed inline
// (9 columns per thread). Blocks [nFK, nFK+21): lane-parallel reduce of the
// NPART M-partials into Mfinal.
__global__ __launch_bounds__(256) void fk_kernel(
    const float* __restrict__ theta, const float* __restrict__ wrist,
    const float* __restrict__ hc, const float* __restrict__ hm,
    const float* __restrict__ Mpart, float* __restrict__ wsA,
    float* __restrict__ Mfinal, int total, int nFK) {
    int blk = blockIdx.x;
    int t = threadIdx.x;
    if (blk >= nFK) {
        __shared__ float sm[256];
        int q = (blk - nFK) * 64 + (t & 63);
        int pg = t >> 6;                // 0..3
        float acc = 0.f;
#pragma unroll
        for (int u = 0; u < 16; ++u) acc += Mpart[(size_t)(pg * 16 + u) * 1392 + q];
        sm[t] = acc;
        __syncthreads();
        if (pg == 0) Mfinal[q] = sm[t] + sm[t + 64] + sm[t + 128] + sm[t + 192];
        return;
    }
    // jt reduce, lane-parallel: 192 threads = 4 p-groups x 48 entries.
    __shared__ float sred[192];
    __shared__ float sj[48];
    if (t < 192) {
        int g = t / 48, o = t - g * 48;
        float acc = 0.f;
#pragma unroll
        for (int u = 0; u < 16; ++u)
            acc += Mpart[(size_t)(g * 16 + u) * 1392 + 1344 + o];
        sred[t] = acc;
    }
    __syncthreads();
    if (t < 48) sj[t] = sred[t] + sred[48 + t] + sred[96 + t] + sred[144 + t];
    __syncthreads();

    int idx = blk * 256 + t;
    if (idx >= total) return;  // total = B*5
    int b = idx / 5, r = idx - b * 5;

    // euler columns [9r, 9r+9) for this thread only
    float e[9];
    {
        const float* th = theta + (size_t)b * 45;
        int base = 9 * r;
#pragma unroll
        for (int col = 0; col < 9; ++col) e[col] = hm[base + col];
        for (int k = 0; k < 45; ++k) {
            float tk = th[k];
            const float* hck = hc + k * 45 + base;
#pragma unroll
            for (int col = 0; col < 9; ++col) e[col] += tk * hck[col];
        }
    }

    float R[9];
    rodrigues9(wrist[b * 3 + 0], wrist[b * 3 + 1], wrist[b * 3 + 2], R);
    float J0x = sj[0], J0y = sj[1], J0z = sj[2];
    float Ap[12];
    Ap[0] = R[0]; Ap[1] = R[1]; Ap[2] = R[2]; Ap[3] = J0x;
    Ap[4] = R[3]; Ap[5] = R[4]; Ap[6] = R[5]; Ap[7] = J0y;
    Ap[8] = R[6]; Ap[9] = R[7]; Ap[10] = R[8]; Ap[11] = J0z;
    float* out = wsA + (size_t)b * 192;
    if (r == 0) {
#pragma unroll
        for (int row = 0; row < 3; ++row) {
            out[row * 4 + 0] = Ap[row * 4 + 0];
            out[row * 4 + 1] = Ap[row * 4 + 1];
            out[row * 4 + 2] = Ap[row * 4 + 2];
            out[row * 4 + 3] = Ap[row * 4 + 3] -
                (Ap[row * 4 + 0] * J0x + Ap[row * 4 + 1] * J0y + Ap[row * 4 + 2] * J0z);
        }
    }
    float px = J0x, py = J0y, pz = J0z;
#pragma unroll
    for (int s = 0; s < 3; ++s) {
        int i = r * 3 + s + 1;
        rodrigues9(e[3 * s + 0], e[3 * s + 1], e[3 * s + 2], R);
        float jx = sj[i * 3 + 0], jy = sj[i * 3 + 1], jz = sj[i * 3 + 2];
        float tx = jx - px, ty = jy - py, tz = jz - pz;
        float An[12];
#pragma unroll
        for (int row = 0; row < 3; ++row) {
            An[row * 4 + 0] = Ap[row * 4 + 0] * R[0] + Ap[row * 4 + 1] * R[3] + Ap[row * 4 + 2] * R[6];
            An[row * 4 + 1] = Ap[row * 4 + 0] * R[1] + Ap[row * 4 + 1] * R[4] + Ap[row * 4 + 2] * R[7];
            An[row * 4 + 2] = Ap[row * 4 + 0] * R[2] + Ap[row * 4 + 1] * R[5] + Ap[row * 4 + 2] * R[8];
            An[row * 4 + 3] = Ap[row * 4 + 3] + Ap[row * 4 + 0] * tx + Ap[row * 4 + 1] * ty + Ap[row * 4 + 2] * tz;
        }
        float* oi = out + i * 12;
#pragma unroll
        for (int row = 0; row < 3; ++row) {
            oi[row * 4 + 0] = An[row * 4 + 0];
            oi[row * 4 + 1] = An[row * 4 + 1];
            oi[row * 4 + 2] = An[row * 4 + 2];
            oi[row * 4 + 3] = An[row * 4 + 3] -
                (An[row * 4 + 0] * jx + An[row * 4 + 1] * jy + An[row * 4 + 2] * jz);
        }
#pragma unroll
        for (int q = 0; q < 12; ++q) Ap[q] = An[q];
        px = jx; py = jy; pz = jz;
    }
}

// K3: blocks [0, nVB): verts with lane = (v_local 0..20, p 0..2).
//   Each wave covers 21 vertices; block (4 waves) covers 84; 13 vblk x 4 waves
//   = 52 vertex-groups = 1092 slots >= 1084. Per batch: 16 independent
//   global_load_dwordx4 of A rows (3 distinct addrs/wave -> L1 broadcast),
//   5 VALU per k per lane. No SMEM operand streams, no LDS.
// blocks [nVB, nVB + B/NBATCH): joints for NBATCH batches each.
__global__ __launch_bounds__(256) void verts_joints_kernel(
    const float* __restrict__ wsA, const float* __restrict__ Mfinal,
    const float* __restrict__ wts, const float* __restrict__ vtpl,
    float* __restrict__ verts, float* __restrict__ jout, int nVB) {
    int bid = blockIdx.x;
    int t = threadIdx.x;

    if (bid < nVB) {
        int vblk = bid % 13;
        int bgrp = bid / 13;
        int wave = t >> 6, lane = t & 63;
        int vl = lane / 3;              // 0..21 (lane 63 -> 21)
        int p = lane - vl * 3;          // 0..2
        int vgrp = vblk * 4 + wave;     // 0..51
        int v = vgrp * 21 + vl;
        bool valid = (lane < 63) && (v < NV);

        float w[16];
        float vx = 0.f, vy = 0.f, vz = 0.f;
        if (valid) {
            const float4* wp = (const float4*)&wts[v * 16];
            float4 q0 = wp[0], q1 = wp[1], q2 = wp[2], q3 = wp[3];
            w[0] = q0.x; w[1] = q0.y; w[2] = q0.z; w[3] = q0.w;
            w[4] = q1.x; w[5] = q1.y; w[6] = q1.z; w[7] = q1.w;
            w[8] = q2.x; w[9] = q2.y; w[10] = q2.z; w[11] = q2.w;
            w[12] = q3.x; w[13] = q3.y; w[14] = q3.z; w[15] = q3.w;
            vx = vtpl[v * 3 + 0]; vy = vtpl[v * 3 + 1]; vz = vtpl[v * 3 + 2];
        } else {
#pragma unroll
            for (int q = 0; q < 16; ++q) w[q] = 0.f;
        }

        int b0 = bgrp * NBATCH;
        int pofs = p * 4;               // p=0 for lane 63 (harmless)
#pragma unroll 1
        for (int bb = 0; bb < NBATCH; ++bb) {
            const float* Ab = wsA + (size_t)(b0 + bb) * 192 + pofs;
            float acc0 = 0.f, acc1 = 0.f;
#pragma unroll
            for (int k = 0; k < 16; k += 2) {
                float4 a0 = *(const float4*)(Ab + k * 12);
                float4 a1 = *(const float4*)(Ab + k * 12 + 12);
                float s0 = fmaf(a0.y, vy, a0.x * vx);
                s0 = fmaf(a0.z, vz, s0) + a0.w;
                acc0 = fmaf(w[k], s0, acc0);
                float s1 = fmaf(a1.y, vy, a1.x * vx);
                s1 = fmaf(a1.z, vz, s1) + a1.w;
                acc1 = fmaf(w[k + 1], s1, acc1);
            }
            if (valid) {
                verts[(size_t)(b0 + bb) * (NV * 3) + v * 3 + p] = acc0 + acc1;
            }
        }
    } else {
        // joints: jout[b, j, c] = sum_k sum_d M[j][k][d] * A[b][k][c*4+d]
        int b0 = (bid - nVB) * NBATCH;
        for (int o = t; o < NBATCH * 63; o += 256) {
            int bl = o / 63;
            int rem = o - bl * 63;
            int j = rem / 3;
            int c = rem - j * 3;
            const float* A = wsA + (size_t)(b0 + bl) * 192 + c * 4;
            const float* Mj = Mfinal + j * 64;
            float acc = 0.f;
#pragma unroll
            for (int k = 0; k < 16; ++k) {
                float4 a = *(const float4*)&A[k * 12];
                float4 m = *(const float4*)&Mj[k * 4];
                acc += a.x * m.x + a.y * m.y + a.z * m.z + a.w * m.w;
            }
            jout[(size_t)(b0 + bl) * 63 + rem] = acc;
        }
    }
}

extern "C" void kernel_launch(void* const* d_in, const int* in_sizes, int n_in,
                              void* d_out, int out_size, void* d_ws, size_t ws_size,
                              hipStream_t stream) {
    const float* theta = (const float*)d_in[1];
    const float* wrist = (const float*)d_in[2];
    const float* vtpl  = (const float*)d_in[3];
    const float* jreg  = (const float*)d_in[4];
    const float* hc    = (const float*)d_in[5];
    const float* hm    = (const float*)d_in[6];
    const float* wts   = (const float*)d_in[7];
    int B = in_sizes[1] / 45;  // 4096

    float* ws     = (float*)d_ws;
    float* wsA    = ws;                            // B*192
    float* Mpart  = ws + (size_t)B * 192;          // NPART*1392
    float* Mfinal = Mpart + (size_t)NPART * 1392;  // 1344
    float* verts  = (float*)d_out;
    float* jout   = verts + (size_t)B * NV * 3;

    prep_kernel<<<NPART, 384, 0, stream>>>(vtpl, jreg, wts, Mpart);
    int nFK = (B * 5 + 255) / 256;
    fk_kernel<<<nFK + 21, 256, 0, stream>>>(theta, wrist, hc, hm, Mpart, wsA,
                                            Mfinal, B * 5, nFK);
    int nVB = 13 * (B / NBATCH);
    verts_joints_kernel<<<nVB + B / NBATCH, 256, 0, stream>>>(
        wsA, Mfinal, wts, vtpl, verts, jout, nVB);
}

// Round 11
// 94.426 us; speedup vs baseline: 1.4195x; 1.4195x over previous
//
#include <hip/hip_runtime.h>

#define NV 1084
#define NPART 64   // precompute partials
#define NBATCH 8   // batches per joints block
#define VCH 46     // verts per chunk
#define NVC 24     // ceil(1084/46)
#define BG 64      // batches per verts block (x3 p = 192 threads)

// ws layout (floats):
//  [0, B*192)            A_rel [B][16][12]
//  next NPART*1392       Mpart[p]: M[21][16][4] (1344) + jt[48]
//  next 1344             Mfinal [21][16][4]
//  next NV*64            G [NV][64]:  G[v][4k+d] = w[v][k] * {vx,vy,vz,1}[d]

__device__ inline void rodrigues9(float x, float y, float z, float R[9]) {
    float n2 = x * x + y * y + z * z + 1e-8f;
    float angle = sqrtf(n2);
    float inv = 1.0f / angle;
    float ax = x * inv, ay = y * inv, az = z * inv;
    float c = cosf(angle), s = sinf(angle);
    float C = 1.0f - c;
    R[0] = 1.0f - C * (ay * ay + az * az);
    R[1] = -s * az + C * ax * ay;
    R[2] = s * ay + C * ax * az;
    R[3] = s * az + C * ax * ay;
    R[4] = 1.0f - C * (ax * ax + az * az);
    R[5] = -s * ax + C * ay * az;
    R[6] = -s * ay + C * ax * az;
    R[7] = s * ax + C * ay * az;
    R[8] = 1.0f - C * (ax * ax + ay * ay);
}

// K1: blocks [0,NPART): partial M/jt over 17 verts each.
//     blocks [NPART, ...): G table, one element per thread.
__global__ __launch_bounds__(384) void prep_kernel(
    const float* __restrict__ vt, const float* __restrict__ jreg,
    const float* __restrict__ wts, float* __restrict__ Mpart,
    float* __restrict__ G) {
    int blk = blockIdx.x;
    int t = threadIdx.x;
    if (blk < NPART) {
        int p = blk;
        int v0 = p * 17, v1 = min(v0 + 17, NV);
        float* mp = Mpart + (size_t)p * 1392;
        if (t < 336) {
            int j = t >> 4, k = t & 15;
            float m0 = 0.f, m1 = 0.f, m2 = 0.f, s = 0.f;
            for (int v = v0; v < v1; ++v) {
                float jw = jreg[v * 21 + j] * wts[v * 16 + k];
                m0 += jw * vt[v * 3 + 0];
                m1 += jw * vt[v * 3 + 1];
                m2 += jw * vt[v * 3 + 2];
                s += jw;
            }
            mp[t * 4 + 0] = m0;
            mp[t * 4 + 1] = m1;
            mp[t * 4 + 2] = m2;
            mp[t * 4 + 3] = s;
        } else if (t < 384) {
            int o = t - 336;
            int j = o / 3, c = o - j * 3;
            float acc = 0.f;
            for (int v = v0; v < v1; ++v) acc += vt[v * 3 + c] * jreg[v * 21 + j];
            mp[1344 + o] = acc;
        }
    } else {
        int idx = (blk - NPART) * 384 + t;
        if (idx < NV * 64) {
            int v = idx >> 6, i = idx & 63;
            int k = i >> 2, d = i & 3;
            float vh = (d == 3) ? 1.f : vt[v * 3 + d];
            G[idx] = wts[v * 16 + k] * vh;
        }
    }
}

// K2: blocks [0, nFK): FK per (batch, chain-role), euler inline.
//     blocks [nFK, nFK+21): lane-parallel reduce of M-partials into Mfinal.
__global__ __launch_bounds__(256) void fk_kernel(
    const float* __restrict__ theta, const float* __restrict__ wrist,
    const float* __restrict__ hc, const float* __restrict__ hm,
    const float* __restrict__ Mpart, float* __restrict__ wsA,
    float* __restrict__ Mfinal, int total, int nFK) {
    int blk = blockIdx.x;
    int t = threadIdx.x;
    if (blk >= nFK) {
        __shared__ float sm[256];
        int q = (blk - nFK) * 64 + (t & 63);
        int pg = t >> 6;
        float acc = 0.f;
#pragma unroll
        for (int u = 0; u < 16; ++u) acc += Mpart[(size_t)(pg * 16 + u) * 1392 + q];
        sm[t] = acc;
        __syncthreads();
        if (pg == 0) Mfinal[q] = sm[t] + sm[t + 64] + sm[t + 128] + sm[t + 192];
        return;
    }
    __shared__ float sred[192];
    __shared__ float sj[48];
    if (t < 192) {
        int g = t / 48, o = t - g * 48;
        float acc = 0.f;
#pragma unroll
        for (int u = 0; u < 16; ++u)
            acc += Mpart[(size_t)(g * 16 + u) * 1392 + 1344 + o];
        sred[t] = acc;
    }
    __syncthreads();
    if (t < 48) sj[t] = sred[t] + sred[48 + t] + sred[96 + t] + sred[144 + t];
    __syncthreads();

    int idx = blk * 256 + t;
    if (idx >= total) return;  // total = B*5
    int b = idx / 5, r = idx - b * 5;

    float e[9];
    {
        const float* th = theta + (size_t)b * 45;
        int base = 9 * r;
#pragma unroll
        for (int col = 0; col < 9; ++col) e[col] = hm[base + col];
        for (int k = 0; k < 45; ++k) {
            float tk = th[k];
            const float* hck = hc + k * 45 + base;
#pragma unroll
            for (int col = 0; col < 9; ++col) e[col] += tk * hck[col];
        }
    }

    float R[9];
    rodrigues9(wrist[b * 3 + 0], wrist[b * 3 + 1], wrist[b * 3 + 2], R);
    float J0x = sj[0], J0y = sj[1], J0z = sj[2];
    float Ap[12];
    Ap[0] = R[0]; Ap[1] = R[1]; Ap[2] = R[2]; Ap[3] = J0x;
    Ap[4] = R[3]; Ap[5] = R[4]; Ap[6] = R[5]; Ap[7] = J0y;
    Ap[8] = R[6]; Ap[9] = R[7]; Ap[10] = R[8]; Ap[11] = J0z;
    float* out = wsA + (size_t)b * 192;
    if (r == 0) {
#pragma unroll
        for (int row = 0; row < 3; ++row) {
            out[row * 4 + 0] = Ap[row * 4 + 0];
            out[row * 4 + 1] = Ap[row * 4 + 1];
            out[row * 4 + 2] = Ap[row * 4 + 2];
            out[row * 4 + 3] = Ap[row * 4 + 3] -
                (Ap[row * 4 + 0] * J0x + Ap[row * 4 + 1] * J0y + Ap[row * 4 + 2] * J0z);
        }
    }
    float px = J0x, py = J0y, pz = J0z;
#pragma unroll
    for (int s = 0; s < 3; ++s) {
        int i = r * 3 + s + 1;
        rodrigues9(e[3 * s + 0], e[3 * s + 1], e[3 * s + 2], R);
        float jx = sj[i * 3 + 0], jy = sj[i * 3 + 1], jz = sj[i * 3 + 2];
        float tx = jx - px, ty = jy - py, tz = jz - pz;
        float An[12];
#pragma unroll
        for (int row = 0; row < 3; ++row) {
            An[row * 4 + 0] = Ap[row * 4 + 0] * R[0] + Ap[row * 4 + 1] * R[3] + Ap[row * 4 + 2] * R[6];
            An[row * 4 + 1] = Ap[row * 4 + 0] * R[1] + Ap[row * 4 + 1] * R[4] + Ap[row * 4 + 2] * R[7];
            An[row * 4 + 2] = Ap[row * 4 + 0] * R[2] + Ap[row * 4 + 1] * R[5] + Ap[row * 4 + 2] * R[8];
            An[row * 4 + 3] = Ap[row * 4 + 3] + Ap[row * 4 + 0] * tx + Ap[row * 4 + 1] * ty + Ap[row * 4 + 2] * tz;
        }
        float* oi = out + i * 12;
#pragma unroll
        for (int row = 0; row < 3; ++row) {
            oi[row * 4 + 0] = An[row * 4 + 0];
            oi[row * 4 + 1] = An[row * 4 + 1];
            oi[row * 4 + 2] = An[row * 4 + 2];
            oi[row * 4 + 3] = An[row * 4 + 3] -
                (An[row * 4 + 0] * jx + An[row * 4 + 1] * jy + An[row * 4 + 2] * jz);
        }
#pragma unroll
        for (int q = 0; q < 12; ++q) Ap[q] = An[q];
        px = jx; py = jy; pz = jz;
    }
}

// K3: blocks [0, nVB): verts. 192 threads = 64 batches x 3 rows (p).
//   Thread (b_local, p) holds A[b][k][4p+d] (64 floats) in VGPRs -- coalesced
//   one-time load -- and loops over a 46-vertex chunk whose G rows are staged
//   in LDS and consumed as broadcast ds_read_b128 (in-order, pipelined).
//   verts[b][v][p] = sum_i G[v][i] * a[i].
// blocks [nVB, nVB + B/NBATCH): joints for NBATCH batches each.
__global__ __launch_bounds__(192) void verts_joints_kernel(
    const float* __restrict__ wsA, const float* __restrict__ Mfinal,
    const float* __restrict__ G, float* __restrict__ verts,
    float* __restrict__ jout, int nVB) {
    int bid = blockIdx.x;
    int t = threadIdx.x;

    if (bid < nVB) {
        int bg = bid / NVC;             // batch group
        int vc = bid - bg * NVC;        // vertex chunk
        int b0 = bg * BG;
        int v0 = vc * VCH;
        int vcnt = min(VCH, NV - v0);

        __shared__ float sG[VCH * 64];
        for (int i = t; i < vcnt * 64; i += 192) sG[i] = G[(size_t)v0 * 64 + i];

        int bl = t / 3, p = t - bl * 3;
        int b = b0 + bl;
        float a[64];
        {
            const float* Ab = wsA + (size_t)b * 192 + p * 4;
#pragma unroll
            for (int k = 0; k < 16; ++k) {
                float4 av = *(const float4*)(Ab + k * 12);
                a[k * 4 + 0] = av.x; a[k * 4 + 1] = av.y;
                a[k * 4 + 2] = av.z; a[k * 4 + 3] = av.w;
            }
        }
        __syncthreads();

        float* outb = verts + (size_t)b * (NV * 3) + p;
#pragma unroll 1
        for (int vl = 0; vl < vcnt; ++vl) {
            const float4* Gp = (const float4*)&sG[vl * 64];
            float acc0 = 0.f, acc1 = 0.f, acc2 = 0.f, acc3 = 0.f;
#pragma unroll
            for (int kk = 0; kk < 4; ++kk) {
                float4 g0 = Gp[kk * 4 + 0];
                float4 g1 = Gp[kk * 4 + 1];
                float4 g2 = Gp[kk * 4 + 2];
                float4 g3 = Gp[kk * 4 + 3];
                const float* ak = &a[kk * 16];
                acc0 = fmaf(g0.x, ak[0], acc0);
                acc1 = fmaf(g0.y, ak[1], acc1);
                acc2 = fmaf(g0.z, ak[2], acc2);
                acc3 = fmaf(g0.w, ak[3], acc3);
                acc0 = fmaf(g1.x, ak[4], acc0);
                acc1 = fmaf(g1.y, ak[5], acc1);
                acc2 = fmaf(g1.z, ak[6], acc2);
                acc3 = fmaf(g1.w, ak[7], acc3);
                acc0 = fmaf(g2.x, ak[8], acc0);
                acc1 = fmaf(g2.y, ak[9], acc1);
                acc2 = fmaf(g2.z, ak[10], acc2);
                acc3 = fmaf(g2.w, ak[11], acc3);
                acc0 = fmaf(g3.x, ak[12], acc0);
                acc1 = fmaf(g3.y, ak[13], acc1);
                acc2 = fmaf(g3.z, ak[14], acc2);
                acc3 = fmaf(g3.w, ak[15], acc3);
            }
            outb[(size_t)(v0 + vl) * 3] = (acc0 + acc1) + (acc2 + acc3);
        }
    } else {
        // joints: jout[b, j, c] = sum_k sum_d M[j][k][d] * A[b][k][c*4+d]
        int b0 = (bid - nVB) * NBATCH;
        for (int o = t; o < NBATCH * 63; o += 192) {
            int bl = o / 63;
            int rem = o - bl * 63;
            int j = rem / 3;
            int c = rem - j * 3;
            const float* A = wsA + (size_t)(b0 + bl) * 192 + c * 4;
            const float* Mj = Mfinal + j * 64;
            float acc = 0.f;
#pragma unroll
            for (int k = 0; k < 16; ++k) {
                float4 av = *(const float4*)&A[k * 12];
                float4 m = *(const float4*)&Mj[k * 4];
                acc += av.x * m.x + av.y * m.y + av.z * m.z + av.w * m.w;
            }
            jout[(size_t)(b0 + bl) * 63 + rem] = acc;
        }
    }
}

extern "C" void kernel_launch(void* const* d_in, const int* in_sizes, int n_in,
                              void* d_out, int out_size, void* d_ws, size_t ws_size,
                              hipStream_t stream) {
    const float* theta = (const float*)d_in[1];
    const float* wrist = (const float*)d_in[2];
    const float* vtpl  = (const float*)d_in[3];
    const float* jreg  = (const float*)d_in[4];
    const float* hc    = (const float*)d_in[5];
    const float* hm    = (const float*)d_in[6];
    const float* wts   = (const float*)d_in[7];
    int B = in_sizes[1] / 45;  // 4096

    float* ws     = (float*)d_ws;
    float* wsA    = ws;                            // B*192
    float* Mpart  = ws + (size_t)B * 192;          // NPART*1392
    float* Mfinal = Mpart + (size_t)NPART * 1392;  // 1344
    float* G      = Mfinal + 1344;                 // NV*64
    float* verts  = (float*)d_out;
    float* jout   = verts + (size_t)B * NV * 3;

    int nG = (NV * 64 + 383) / 384;
    prep_kernel<<<NPART + nG, 384, 0, stream>>>(vtpl, jreg, wts, Mpart, G);
    int nFK = (B * 5 + 255) / 256;
    fk_kernel<<<nFK + 21, 256, 0, stream>>>(theta, wrist, hc, hm, Mpart, wsA,
                                            Mfinal, B * 5, nFK);
    int nVB = (B / BG) * NVC;
    verts_joints_kernel<<<nVB + B / NBATCH, 192, 0, stream>>>(
        wsA, Mfinal, G, verts, jout, nVB);
}

// Round 12
// 56.953 us; speedup vs baseline: 2.3534x; 1.6580x over previous
//
#include <hip/hip_runtime.h>

#define NV 1084
#define NVPAD 1088
#define NPART 64   // precompute partials
#define NBATCH 8   // batches per joints block

typedef __attribute__((ext_vector_type(8))) short short8v;
typedef __attribute__((ext_vector_type(4))) float f32x4;

__device__ inline unsigned short f2bf(float f) {
    unsigned int u = __float_as_uint(f);
    unsigned int r = (u + 0x7FFFu + ((u >> 16) & 1u)) >> 16;
    return (unsigned short)r;
}

// ws layout:
//  wsA    : B*192 f32          A_rel [B][16][12]
//  Mpart  : NPART*1392 f32     partials: M[21][16][4] (1344) + jt[48]
//  Mfinal : 1344 f32
//  Gbf    : NVPAD*64 ushort    G[v][4k+d] = w[v][k]*{vx,vy,vz,1}[d]  (bf16)
//  Abf    : 3B*64 ushort       Abf[3b+p][4k+d] = A_rel[b][k][4p+d]   (bf16)

__device__ inline void rodrigues9(float x, float y, float z, float R[9]) {
    float n2 = x * x + y * y + z * z + 1e-8f;
    float angle = sqrtf(n2);
    float inv = 1.0f / angle;
    float ax = x * inv, ay = y * inv, az = z * inv;
    float c = cosf(angle), s = sinf(angle);
    float C = 1.0f - c;
    R[0] = 1.0f - C * (ay * ay + az * az);
    R[1] = -s * az + C * ax * ay;
    R[2] = s * ay + C * ax * az;
    R[3] = s * az + C * ax * ay;
    R[4] = 1.0f - C * (ax * ax + az * az);
    R[5] = -s * ax + C * ay * az;
    R[6] = -s * ay + C * ax * az;
    R[7] = s * ax + C * ay * az;
    R[8] = 1.0f - C * (ax * ax + ay * ay);
}

// K1: blocks [0,NPART): partial M/jt over 17 verts each.
//     blocks [NPART,NPART+nG): Gbf table (bf16), one element per thread.
__global__ __launch_bounds__(384) void prep_kernel(
    const float* __restrict__ vt, const float* __restrict__ jreg,
    const float* __restrict__ wts, float* __restrict__ Mpart,
    unsigned short* __restrict__ Gbf) {
    int blk = blockIdx.x;
    int t = threadIdx.x;
    if (blk < NPART) {
        int p = blk;
        int v0 = p * 17, v1 = min(v0 + 17, NV);
        float* mp = Mpart + (size_t)p * 1392;
        if (t < 336) {
            int j = t >> 4, k = t & 15;
            float m0 = 0.f, m1 = 0.f, m2 = 0.f, s = 0.f;
            for (int v = v0; v < v1; ++v) {
                float jw = jreg[v * 21 + j] * wts[v * 16 + k];
                m0 += jw * vt[v * 3 + 0];
                m1 += jw * vt[v * 3 + 1];
                m2 += jw * vt[v * 3 + 2];
                s += jw;
            }
            mp[t * 4 + 0] = m0;
            mp[t * 4 + 1] = m1;
            mp[t * 4 + 2] = m2;
            mp[t * 4 + 3] = s;
        } else if (t < 384) {
            int o = t - 336;
            int j = o / 3, c = o - j * 3;
            float acc = 0.f;
            for (int v = v0; v < v1; ++v) acc += vt[v * 3 + c] * jreg[v * 21 + j];
            mp[1344 + o] = acc;
        }
    } else {
        int idx = (blk - NPART) * 384 + t;
        if (idx < NVPAD * 64) {
            int v = idx >> 6, i = idx & 63;
            int k = i >> 2, d = i & 3;
            float val = 0.f;
            if (v < NV) {
                float vh = (d == 3) ? 1.f : vt[v * 3 + d];
                val = wts[v * 16 + k] * vh;
            }
            Gbf[idx] = f2bf(val);
        }
    }
}

// K2: blocks [0, nFK): FK per (batch, chain-role), euler inline; writes both
//     f32 A_rel (for joints) and bf16 Abf rows (for the MFMA GEMM).
//     blocks [nFK, nFK+21): lane-parallel reduce of M-partials into Mfinal.
__global__ __launch_bounds__(256) void fk_kernel(
    const float* __restrict__ theta, const float* __restrict__ wrist,
    const float* __restrict__ hc, const float* __restrict__ hm,
    const float* __restrict__ Mpart, float* __restrict__ wsA,
    float* __restrict__ Mfinal, unsigned short* __restrict__ Abf,
    int total, int nFK) {
    int blk = blockIdx.x;
    int t = threadIdx.x;
    if (blk >= nFK) {
        __shared__ float sm[256];
        int q = (blk - nFK) * 64 + (t & 63);
        int pg = t >> 6;
        float acc = 0.f;
#pragma unroll
        for (int u = 0; u < 16; ++u) acc += Mpart[(size_t)(pg * 16 + u) * 1392 + q];
        sm[t] = acc;
        __syncthreads();
        if (pg == 0) Mfinal[q] = sm[t] + sm[t + 64] + sm[t + 128] + sm[t + 192];
        return;
    }
    __shared__ float sred[192];
    __shared__ float sj[48];
    if (t < 192) {
        int g = t / 48, o = t - g * 48;
        float acc = 0.f;
#pragma unroll
        for (int u = 0; u < 16; ++u)
            acc += Mpart[(size_t)(g * 16 + u) * 1392 + 1344 + o];
        sred[t] = acc;
    }
    __syncthreads();
    if (t < 48) sj[t] = sred[t] + sred[48 + t] + sred[96 + t] + sred[144 + t];
    __syncthreads();

    int idx = blk * 256 + t;
    if (idx >= total) return;  // total = B*5
    int b = idx / 5, r = idx - b * 5;

    float e[9];
    {
        const float* th = theta + (size_t)b * 45;
        int base = 9 * r;
#pragma unroll
        for (int col = 0; col < 9; ++col) e[col] = hm[base + col];
        for (int k = 0; k < 45; ++k) {
            float tk = th[k];
            const float* hck = hc + k * 45 + base;
#pragma unroll
            for (int col = 0; col < 9; ++col) e[col] += tk * hck[col];
        }
    }

    float R[9];
    rodrigues9(wrist[b * 3 + 0], wrist[b * 3 + 1], wrist[b * 3 + 2], R);
    float J0x = sj[0], J0y = sj[1], J0z = sj[2];
    float Ap[12];
    Ap[0] = R[0]; Ap[1] = R[1]; Ap[2] = R[2]; Ap[3] = J0x;
    Ap[4] = R[3]; Ap[5] = R[4]; Ap[6] = R[5]; Ap[7] = J0y;
    Ap[8] = R[6]; Ap[9] = R[7]; Ap[10] = R[8]; Ap[11] = J0z;
    float* out = wsA + (size_t)b * 192;
    if (r == 0) {
#pragma unroll
        for (int row = 0; row < 3; ++row) {
            float a0 = Ap[row * 4 + 0], a1 = Ap[row * 4 + 1], a2 = Ap[row * 4 + 2];
            float a3 = Ap[row * 4 + 3] - (a0 * J0x + a1 * J0y + a2 * J0z);
            out[row * 4 + 0] = a0;
            out[row * 4 + 1] = a1;
            out[row * 4 + 2] = a2;
            out[row * 4 + 3] = a3;
            ushort4 h;
            h.x = f2bf(a0); h.y = f2bf(a1); h.z = f2bf(a2); h.w = f2bf(a3);
            *(ushort4*)(Abf + (size_t)(3 * b + row) * 64) = h;
        }
    }
    float px = J0x, py = J0y, pz = J0z;
#pragma unroll
    for (int s = 0; s < 3; ++s) {
        int i = r * 3 + s + 1;
        rodrigues9(e[3 * s + 0], e[3 * s + 1], e[3 * s + 2], R);
        float jx = sj[i * 3 + 0], jy = sj[i * 3 + 1], jz = sj[i * 3 + 2];
        float tx = jx - px, ty = jy - py, tz = jz - pz;
        float An[12];
#pragma unroll
        for (int row = 0; row < 3; ++row) {
            An[row * 4 + 0] = Ap[row * 4 + 0] * R[0] + Ap[row * 4 + 1] * R[3] + Ap[row * 4 + 2] * R[6];
            An[row * 4 + 1] = Ap[row * 4 + 0] * R[1] + Ap[row * 4 + 1] * R[4] + Ap[row * 4 + 2] * R[7];
            An[row * 4 + 2] = Ap[row * 4 + 0] * R[2] + Ap[row * 4 + 1] * R[5] + Ap[row * 4 + 2] * R[8];
            An[row * 4 + 3] = Ap[row * 4 + 3] + Ap[row * 4 + 0] * tx + Ap[row * 4 + 1] * ty + Ap[row * 4 + 2] * tz;
        }
        float* oi = out + i * 12;
#pragma unroll
        for (int row = 0; row < 3; ++row) {
            float a0 = An[row * 4 + 0], a1 = An[row * 4 + 1], a2 = An[row * 4 + 2];
            float a3 = An[row * 4 + 3] - (a0 * jx + a1 * jy + a2 * jz);
            oi[row * 4 + 0] = a0;
            oi[row * 4 + 1] = a1;
            oi[row * 4 + 2] = a2;
            oi[row * 4 + 3] = a3;
            ushort4 h;
            h.x = f2bf(a0); h.y = f2bf(a1); h.z = f2bf(a2); h.w = f2bf(a3);
            *(ushort4*)(Abf + (size_t)(3 * b + row) * 64 + 4 * i) = h;
        }
#pragma unroll
        for (int q = 0; q < 12; ++q) Ap[q] = An[q];
        px = jx; py = jy; pz = jz;
    }
}

// K3: blocks [0, nVB): MFMA GEMM  out[M=3B][N=NVPAD] = Abf[M][64] x Gbf^T.
//   Block = 4 waves; wave w owns M-tile (Mblk*64 + w*16), N-quarter nq
//   covers 17 N-tiles of 16. Per tile: 2 B-frag 16B loads + 2 MFMA + 4
//   masked stores. A-frags loaded once. No LDS.
// blocks [nVB, nVB + B/NBATCH): joints (f32 path) for NBATCH batches each.
__global__ __launch_bounds__(256) void verts_joints_kernel(
    const float* __restrict__ wsA, const float* __restrict__ Mfinal,
    const unsigned short* __restrict__ Abf, const unsigned short* __restrict__ Gbf,
    float* __restrict__ verts, float* __restrict__ jout, int nVB) {
    int bid = blockIdx.x;
    int t = threadIdx.x;

    if (bid < nVB) {
        int wv = t >> 6, lane = t & 63;
        int Mblk = bid >> 2, nq = bid & 3;
        int Mbase = Mblk * 64 + wv * 16;
        int lrow = lane & 15, lk = lane >> 4;

        const unsigned short* Ar = Abf + (size_t)(Mbase + lrow) * 64 + lk * 8;
        short8v a0 = *(const short8v*)Ar;
        short8v a1 = *(const short8v*)(Ar + 32);

        // store bases for the 4 accumulator rows (m = Mbase + lk*4 + q)
        int mb = Mbase + lk * 4;
        int base[4];
#pragma unroll
        for (int q = 0; q < 4; ++q) {
            int m = mb + q;
            int bq = m / 3;
            int pq = m - 3 * bq;
            base[q] = bq * (NV * 3) + pq;
        }

        for (int ntl = 0; ntl < 17; ++ntl) {
            int v0 = (nq * 17 + ntl) * 16;
            int v = v0 + lrow;
            const unsigned short* Br = Gbf + (size_t)v * 64 + lk * 8;
            short8v g0 = *(const short8v*)Br;
            short8v g1 = *(const short8v*)(Br + 32);
            f32x4 acc = {0.f, 0.f, 0.f, 0.f};
            acc = __builtin_amdgcn_mfma_f32_16x16x32_bf16(a0, g0, acc, 0, 0, 0);
            acc = __builtin_amdgcn_mfma_f32_16x16x32_bf16(a1, g1, acc, 0, 0, 0);
            if (v < NV) {
                int vo = v * 3;
                verts[base[0] + vo] = acc[0];
                verts[base[1] + vo] = acc[1];
                verts[base[2] + vo] = acc[2];
                verts[base[3] + vo] = acc[3];
            }
        }
    } else {
        // joints: jout[b, j, c] = sum_k sum_d M[j][k][d] * A[b][k][c*4+d]
        int b0 = (bid - nVB) * NBATCH;
        for (int o = t; o < NBATCH * 63; o += 256) {
            int bl = o / 63;
            int rem = o - bl * 63;
            int j = rem / 3;
            int c = rem - j * 3;
            const float* A = wsA + (size_t)(b0 + bl) * 192 + c * 4;
            const float* Mj = Mfinal + j * 64;
            float acc = 0.f;
#pragma unroll
            for (int k = 0; k < 16; ++k) {
                float4 av = *(const float4*)&A[k * 12];
                float4 m = *(const float4*)&Mj[k * 4];
                acc += av.x * m.x + av.y * m.y + av.z * m.z + av.w * m.w;
            }
            jout[(size_t)(b0 + bl) * 63 + rem] = acc;
        }
    }
}

extern "C" void kernel_launch(void* const* d_in, const int* in_sizes, int n_in,
                              void* d_out, int out_size, void* d_ws, size_t ws_size,
                              hipStream_t stream) {
    const float* theta = (const float*)d_in[1];
    const float* wrist = (const float*)d_in[2];
    const float* vtpl  = (const float*)d_in[3];
    const float* jreg  = (const float*)d_in[4];
    const float* hc    = (const float*)d_in[5];
    const float* hm    = (const float*)d_in[6];
    const float* wts   = (const float*)d_in[7];
    int B = in_sizes[1] / 45;  // 4096

    float* ws     = (float*)d_ws;
    float* wsA    = ws;                            // B*192 f32
    float* Mpart  = ws + (size_t)B * 192;          // NPART*1392 f32
    float* Mfinal = Mpart + (size_t)NPART * 1392;  // 1344 f32
    unsigned short* Gbf = (unsigned short*)(Mfinal + 1344);  // NVPAD*64 ushort
    unsigned short* Abf = Gbf + (size_t)NVPAD * 64;          // 3B*64 ushort
    float* verts  = (float*)d_out;
    float* jout   = verts + (size_t)B * NV * 3;

    int nG = (NVPAD * 64 + 383) / 384;             // 182
    prep_kernel<<<NPART + nG, 384, 0, stream>>>(vtpl, jreg, wts, Mpart, Gbf);
    int nFK = (B * 5 + 255) / 256;
    fk_kernel<<<nFK + 21, 256, 0, stream>>>(theta, wrist, hc, hm, Mpart, wsA,
                                            Mfinal, Abf, B * 5, nFK);
    int nVB = ((3 * B) / 64) * 4;                  // 768 for B=4096
    verts_joints_kernel<<<nVB + B / NBATCH, 256, 0, stream>>>(
        wsA, Mfinal, Abf, Gbf, verts, jout, nVB);
}